// Round 1
// 400.763 us; speedup vs baseline: 1.1406x; 1.1406x over previous
//
#include <hip/hip_runtime.h>

constexpr int BB = 4, SS = 2048, HH = 1024, NH = 16, HD = 64;
constexpr int M = BB * SS;  // 8192 rows for all GEMMs

typedef short          bf16x8 __attribute__((ext_vector_type(8)));
typedef unsigned short u16x8  __attribute__((ext_vector_type(8)));
typedef float          f32x4  __attribute__((ext_vector_type(4)));

// round-half-up bf16 cvt (differs from RNE only on exact ties)
__device__ __forceinline__ unsigned short f2bf(float f) {
    union { float f; unsigned u; } c; c.f = f;
    return (unsigned short)((c.u + 0x8000u) >> 16);
}
__device__ __forceinline__ unsigned packbf2(float lo, float hi) {
    return (unsigned)f2bf(lo) | ((unsigned)f2bf(hi) << 16);
}
__device__ __forceinline__ u16x8 pack8(const float4& x, const float4& y) {
    u16x8 r = { f2bf(x.x), f2bf(x.y), f2bf(x.z), f2bf(x.w),
                f2bf(y.x), f2bf(y.y), f2bf(y.z), f2bf(y.w) };
    return r;
}

// ---------------------------------------------------------------------------
// Wq/Wk/Wv fp32 [k][n] -> bf16 transposed [n][k], 64x64 LDS tiles.
// Output: WT + z*HH*HH.  Tiny one-shot kernel (~12 MB traffic).
// ---------------------------------------------------------------------------
__global__ __launch_bounds__(256) void wT_k(
    const float* __restrict__ Wq, const float* __restrict__ Wk,
    const float* __restrict__ Wv, unsigned short* __restrict__ WT)
{
    const int z = blockIdx.z;
    const float* W = (z == 0) ? Wq : (z == 1) ? Wk : Wv;
    unsigned short* D = WT + (size_t)z * HH * HH;
    __shared__ __attribute__((aligned(16))) unsigned short T[64][72];

    const int tid = threadIdx.x;
    const int kB = blockIdx.x * 64, nB = blockIdx.y * 64;
    const int r = tid >> 2, c0 = (tid & 3) * 16;
#pragma unroll
    for (int j = 0; j < 4; ++j) {
        float4 w = *(const float4*)(W + (size_t)(kB + r) * HH + nB + c0 + j * 4);
        T[c0 + j * 4 + 0][r] = f2bf(w.x);
        T[c0 + j * 4 + 1][r] = f2bf(w.y);
        T[c0 + j * 4 + 2][r] = f2bf(w.z);
        T[c0 + j * 4 + 3][r] = f2bf(w.w);
    }
    __syncthreads();
    *(u16x8*)(D + (size_t)(nB + r) * HH + kB + c0)     = *(const u16x8*)&T[r][c0];
    *(u16x8*)(D + (size_t)(nB + r) * HH + kB + c0 + 8) = *(const u16x8*)&T[r][c0 + 8];
}

// ---------------------------------------------------------------------------
// QKV GEMM, 128x128 tile, register-prefetched.  A = X fp32 (cvt on stage,
// vector store), B = pre-transposed bf16 WT[n][k] (pure vector stage).
// Q -> bf16 [b,nh,s,hd]; K,V -> fp32 [b,nh,s,hd] (final outputs).
// ---------------------------------------------------------------------------
__global__ __launch_bounds__(256) void qkv_gemm(
    const float* __restrict__ X, const unsigned short* __restrict__ WT,
    const float* __restrict__ bq, const float* __restrict__ bk, const float* __restrict__ bv,
    unsigned short* __restrict__ Qd, float* __restrict__ Kd, float* __restrict__ Vd)
{
    const int z = blockIdx.z;
    const unsigned short* Wg = WT + (size_t)z * HH * HH;
    const float* bias = (z == 0) ? bq : (z == 1) ? bk : bv;

    __shared__ __attribute__((aligned(16))) unsigned short Al[128][40];
    __shared__ __attribute__((aligned(16))) unsigned short Bl[128][40];  // Bl[n][k]

    const int tid  = threadIdx.x;
    const int wave = tid >> 6, lane = tid & 63;
    const int lrow = lane & 15, lq = lane >> 4;
    const int rQ = (wave >> 1) * 64, cQ = (wave & 1) * 64;
    const int mBase = blockIdx.x * 128, nBase = blockIdx.y * 128;

    f32x4 acc[4][4] = {};

    const int arow = tid >> 1, acol = (tid & 1) * 16;  // 128 rows x 32 cols, 16 elems/thread

    const float*          Ap = X  + (size_t)(mBase + arow) * HH + acol;
    const unsigned short* Bp = Wg + (size_t)(nBase + arow) * HH + acol;

    float4 a[4]; u16x8 b0, b1;
    float4 an[4]; u16x8 b0n, b1n;
#pragma unroll
    for (int c = 0; c < 4; ++c) a[c] = *(const float4*)(Ap + c * 4);
    b0 = *(const u16x8*)Bp; b1 = *(const u16x8*)(Bp + 8);
    Ap += 32; Bp += 32;

    for (int k0 = 0; k0 < HH; k0 += 32) {
        __syncthreads();  // prior fragment reads done
        *(u16x8*)&Al[arow][acol]     = pack8(a[0], a[1]);
        *(u16x8*)&Al[arow][acol + 8] = pack8(a[2], a[3]);
        *(u16x8*)&Bl[arow][acol]     = b0;
        *(u16x8*)&Bl[arow][acol + 8] = b1;
        if (k0 + 32 < HH) {  // prefetch next K-slice while this one computes
#pragma unroll
            for (int c = 0; c < 4; ++c) an[c] = *(const float4*)(Ap + c * 4);
            b0n = *(const u16x8*)Bp; b1n = *(const u16x8*)(Bp + 8);
            Ap += 32; Bp += 32;
        }
        __syncthreads();

        bf16x8 af[4], bf[4];
#pragma unroll
        for (int i = 0; i < 4; ++i) af[i] = *(const bf16x8*)&Al[rQ + i * 16 + lrow][lq * 8];
#pragma unroll
        for (int j = 0; j < 4; ++j) bf[j] = *(const bf16x8*)&Bl[cQ + j * 16 + lrow][lq * 8];
#pragma unroll
        for (int i = 0; i < 4; ++i)
#pragma unroll
            for (int j = 0; j < 4; ++j)
                acc[i][j] = __builtin_amdgcn_mfma_f32_16x16x32_bf16(af[i], bf[j], acc[i][j], 0, 0, 0);

#pragma unroll
        for (int c = 0; c < 4; ++c) a[c] = an[c];
        b0 = b0n; b1 = b1n;
    }

#pragma unroll
    for (int j = 0; j < 4; ++j) {
        int   n  = nBase + cQ + j * 16 + lrow;
        float bv = bias[n];
        int   h = n >> 6, d = n & 63;
#pragma unroll
        for (int i = 0; i < 4; ++i) {
#pragma unroll
            for (int r = 0; r < 4; ++r) {
                int   m   = mBase + rQ + i * 16 + lq * 4 + r;
                float val = acc[i][j][r] + bv;
                int   b = m >> 11, s = m & (SS - 1);
                size_t idx = ((size_t)(b * NH + h) * SS + s) * HD + d;
                if (z == 0)      Qd[idx] = f2bf(val);
                else if (z == 1) Kd[idx] = val;
                else             Vd[idx] = val;
            }
        }
    }
}

// ---------------------------------------------------------------------------
// Output projection, 128x128, register-prefetched.  A = ctx bf16 (vector
// stage), W fp32 staged via k-pair-packed b32 transposed stores (4-way max).
// ---------------------------------------------------------------------------
__global__ __launch_bounds__(256) void proj_gemm(
    const unsigned short* __restrict__ X, const float* __restrict__ Wm,
    const float* __restrict__ bias, float* __restrict__ dst)
{
    __shared__ __attribute__((aligned(16))) unsigned short Al[128][40];
    __shared__ __attribute__((aligned(16))) unsigned short Wt[128][40];  // Wt[n][k]

    const int tid  = threadIdx.x;
    const int wave = tid >> 6, lane = tid & 63;
    const int lrow = lane & 15, lq = lane >> 4;
    const int rQ = (wave >> 1) * 64, cQ = (wave & 1) * 64;
    const int mBase = blockIdx.x * 128, nBase = blockIdx.y * 128;

    f32x4 acc[4][4] = {};

    const int arow = tid >> 1, acol = (tid & 1) * 16;
    const int wcol = (tid & 15) * 8, wrow = (tid >> 4) * 2;  // k-pair transposer

    const unsigned short* Ap = X + (size_t)(mBase + arow) * HH + acol;
    const float*          Wp = Wm + (size_t)wrow * HH + nBase + wcol;

    u16x8 a0, a1, a0n, a1n;
    float4 w0a, w0b, w1a, w1b, w0an, w0bn, w1an, w1bn;
    a0 = *(const u16x8*)Ap; a1 = *(const u16x8*)(Ap + 8);
    w0a = *(const float4*)(Wp);      w0b = *(const float4*)(Wp + 4);
    w1a = *(const float4*)(Wp + HH); w1b = *(const float4*)(Wp + HH + 4);
    Ap += 32; Wp += (size_t)32 * HH;

    for (int k0 = 0; k0 < HH; k0 += 32) {
        __syncthreads();
        *(u16x8*)&Al[arow][acol]     = a0;
        *(u16x8*)&Al[arow][acol + 8] = a1;
        *(unsigned*)&Wt[wcol + 0][wrow] = packbf2(w0a.x, w1a.x);
        *(unsigned*)&Wt[wcol + 1][wrow] = packbf2(w0a.y, w1a.y);
        *(unsigned*)&Wt[wcol + 2][wrow] = packbf2(w0a.z, w1a.z);
        *(unsigned*)&Wt[wcol + 3][wrow] = packbf2(w0a.w, w1a.w);
        *(unsigned*)&Wt[wcol + 4][wrow] = packbf2(w0b.x, w1b.x);
        *(unsigned*)&Wt[wcol + 5][wrow] = packbf2(w0b.y, w1b.y);
        *(unsigned*)&Wt[wcol + 6][wrow] = packbf2(w0b.z, w1b.z);
        *(unsigned*)&Wt[wcol + 7][wrow] = packbf2(w0b.w, w1b.w);
        if (k0 + 32 < HH) {
            a0n = *(const u16x8*)Ap; a1n = *(const u16x8*)(Ap + 8);
            w0an = *(const float4*)(Wp);      w0bn = *(const float4*)(Wp + 4);
            w1an = *(const float4*)(Wp + HH); w1bn = *(const float4*)(Wp + HH + 4);
            Ap += 32; Wp += (size_t)32 * HH;
        }
        __syncthreads();

        bf16x8 af[4], bf[4];
#pragma unroll
        for (int i = 0; i < 4; ++i) af[i] = *(const bf16x8*)&Al[rQ + i * 16 + lrow][lq * 8];
#pragma unroll
        for (int j = 0; j < 4; ++j) bf[j] = *(const bf16x8*)&Wt[cQ + j * 16 + lrow][lq * 8];
#pragma unroll
        for (int i = 0; i < 4; ++i)
#pragma unroll
            for (int j = 0; j < 4; ++j)
                acc[i][j] = __builtin_amdgcn_mfma_f32_16x16x32_bf16(af[i], bf[j], acc[i][j], 0, 0, 0);

        a0 = a0n; a1 = a1n;
        w0a = w0an; w0b = w0bn; w1a = w1an; w1b = w1bn;
    }

#pragma unroll
    for (int j = 0; j < 4; ++j) {
        int   n  = nBase + cQ + j * 16 + lrow;
        float bv = bias[n];
#pragma unroll
        for (int i = 0; i < 4; ++i)
#pragma unroll
            for (int r = 0; r < 4; ++r) {
                int m = mBase + rQ + i * 16 + lq * 4 + r;
                dst[(size_t)m * HH + n] = acc[i][j][r] + bv;
            }
    }
}

// ---------------------------------------------------------------------------
// Causal flash attention, QBLK=128 / 8 waves / KVBLK=64.
// - No-max online softmax (|s| small; exp safe), l via ones-MFMA.
// - Q fragments hoisted to registers; Q's LDS tile is overlaid with Ps
//   (both are wave-private row ranges -> race-free, saves 18 KB LDS).
// - Vt is XOR-swizzled in 16B granules: col ^= (d>>3)<<3. Transpose stores
//   land 2 lanes/bank (free); fragment reads stay uniform (conflict-free).
// - Register prefetch of next K/V tile; waves fully below the diagonal
//   skip compute on masked tiles (wave-uniform branch).
// Grid: (S/128 reversed, B*NH) x 512 threads.  2 syncthreads per k-tile.
// ---------------------------------------------------------------------------
__global__ __launch_bounds__(512, 4) void attn_k(
    const unsigned short* __restrict__ Qb, const float* __restrict__ Kb,
    const float* __restrict__ Vb, unsigned short* __restrict__ ctx)
{
    __shared__ __attribute__((aligned(16))) unsigned short QPs[128][72];  // Q tile, then P
    __shared__ __attribute__((aligned(16))) unsigned short Ks[64][72];
    __shared__ __attribute__((aligned(16))) unsigned short Vt[64][72];    // Vt[d][s^swz]

    const int tid  = threadIdx.x;
    const int wave = tid >> 6, lane = tid & 63;
    const int lrow = lane & 15, lq = lane >> 4;
    const int qb = (SS / 128 - 1) - blockIdx.x;  // long blocks launch first
    const int bh = blockIdx.y;
    const int qBase = qb * 128;
    const int wq = qBase + wave * 16;            // this wave's first q row

    const unsigned short* Q = Qb + (size_t)bh * SS * HD;
    const float*          K = Kb + (size_t)bh * SS * HD;
    const float*          V = Vb + (size_t)bh * SS * HD;

    // ---- stage Q tile (128x64 bf16), 16 shorts/thread ----
    {
        const int qr = tid >> 2, qc = (tid & 3) * 16;
        *(u16x8*)&QPs[qr][qc]     = *(const u16x8*)(Q + (size_t)(qBase + qr) * HD + qc);
        *(u16x8*)&QPs[qr][qc + 8] = *(const u16x8*)(Q + (size_t)(qBase + qr) * HD + qc + 8);
    }
    __syncthreads();
    // hoist this wave's Q fragments into registers; QPs becomes the P buffer
    const bf16x8 qf0 = *(const bf16x8*)&QPs[wave * 16 + lrow][lq * 8];
    const bf16x8 qf1 = *(const bf16x8*)&QPs[wave * 16 + lrow][32 + lq * 8];

    const short one = (short)0x3F80;  // bf16 1.0
    const bf16x8 ones = { one, one, one, one, one, one, one, one };

    f32x4 o[4] = {};
    f32x4 lacc = {};

    // K/V staging mapping: 512 threads, 8 floats each
    const int ldr = tid >> 3;                 // K/V row 0..63
    const int fck = (tid & 7) * 8;            // 8-col chunk base
    const int vsw = ldr ^ ((tid & 7) << 3);   // swizzled Vt column for this thread

    float4 ka[2], va[2], kn[2], vn[2];
    {
        const float* Kp = K + (size_t)ldr * HD + fck;
        const float* Vp = V + (size_t)ldr * HD + fck;
        ka[0] = *(const float4*)(Kp); ka[1] = *(const float4*)(Kp + 4);
        va[0] = *(const float4*)(Vp); va[1] = *(const float4*)(Vp + 4);
    }

    const int nkt = 2 * qb + 2;
    for (int kt = 0; kt < nkt; ++kt) {
        __syncthreads();  // prior iter's Ks/Vt fragment reads done
        *(u16x8*)&Ks[ldr][fck] = pack8(ka[0], ka[1]);
        Vt[fck + 0][vsw] = f2bf(va[0].x);
        Vt[fck + 1][vsw] = f2bf(va[0].y);
        Vt[fck + 2][vsw] = f2bf(va[0].z);
        Vt[fck + 3][vsw] = f2bf(va[0].w);
        Vt[fck + 4][vsw] = f2bf(va[1].x);
        Vt[fck + 5][vsw] = f2bf(va[1].y);
        Vt[fck + 6][vsw] = f2bf(va[1].z);
        Vt[fck + 7][vsw] = f2bf(va[1].w);
        if (kt + 1 < nkt) {  // prefetch next K/V tile; stays in flight through compute
            const float* Kp = K + (size_t)((kt + 1) * 64 + ldr) * HD + fck;
            const float* Vp = V + (size_t)((kt + 1) * 64 + ldr) * HD + fck;
            kn[0] = *(const float4*)(Kp); kn[1] = *(const float4*)(Kp + 4);
            vn[0] = *(const float4*)(Vp); vn[1] = *(const float4*)(Vp + 4);
        }
        __syncthreads();

        const int kbase = kt * 64;
        if (kbase <= wq + 15) {  // wave-uniform: tile not fully masked for this wave
            // S = Q K^T  (C-layout: row = wq + lq*4 + rr, col = kbase + nt*16 + lrow)
            f32x4 s[4];
#pragma unroll
            for (int nt = 0; nt < 4; ++nt) {
                bf16x8 kf0 = *(const bf16x8*)&Ks[nt * 16 + lrow][lq * 8];
                bf16x8 kf1 = *(const bf16x8*)&Ks[nt * 16 + lrow][32 + lq * 8];
                f32x4  t   = {};
                t = __builtin_amdgcn_mfma_f32_16x16x32_bf16(qf0, kf0, t, 0, 0, 0);
                t = __builtin_amdgcn_mfma_f32_16x16x32_bf16(qf1, kf1, t, 0, 0, 0);
                s[nt] = t;
            }

#pragma unroll
            for (int nt = 0; nt < 4; ++nt)
#pragma unroll
                for (int rr = 0; rr < 4; ++rr) s[nt][rr] *= 0.125f;
            if (kbase + 63 > wq) {  // wave-uniform: diagonal tile -> element mask
#pragma unroll
                for (int nt = 0; nt < 4; ++nt)
#pragma unroll
                    for (int rr = 0; rr < 4; ++rr)
                        if (kbase + nt * 16 + lrow > wq + lq * 4 + rr) s[nt][rr] = -1e30f;
            }

            // P = exp(S); write to wave-private QPs rows (no barrier needed)
#pragma unroll
            for (int nt = 0; nt < 4; ++nt)
#pragma unroll
                for (int rr = 0; rr < 4; ++rr)
                    QPs[wave * 16 + lq * 4 + rr][nt * 16 + lrow] = f2bf(__expf(s[nt][rr]));

            bf16x8 pf0 = *(const bf16x8*)&QPs[wave * 16 + lrow][lq * 8];
            bf16x8 pf1 = *(const bf16x8*)&QPs[wave * 16 + lrow][32 + lq * 8];

            // l += P·1  (row sums via matrix pipe)
            lacc = __builtin_amdgcn_mfma_f32_16x16x32_bf16(pf0, ones, lacc, 0, 0, 0);
            lacc = __builtin_amdgcn_mfma_f32_16x16x32_bf16(pf1, ones, lacc, 0, 0, 0);

            // O += P V   (Vt reads use the store-side XOR swizzle)
#pragma unroll
            for (int nt = 0; nt < 4; ++nt) {
                const int row  = nt * 16 + lrow;
                const int cswz = (row >> 3) << 3;
                bf16x8 vf0 = *(const bf16x8*)&Vt[row][(lq * 8) ^ cswz];
                bf16x8 vf1 = *(const bf16x8*)&Vt[row][(32 + lq * 8) ^ cswz];
                o[nt] = __builtin_amdgcn_mfma_f32_16x16x32_bf16(pf0, vf0, o[nt], 0, 0, 0);
                o[nt] = __builtin_amdgcn_mfma_f32_16x16x32_bf16(pf1, vf1, o[nt], 0, 0, 0);
            }
        }

        ka[0] = kn[0]; ka[1] = kn[1]; va[0] = vn[0]; va[1] = vn[1];
    }

    // epilogue: O /= l, write ctx bf16 as [b, s, h*HD + d]
    float linv[4];
#pragma unroll
    for (int rr = 0; rr < 4; ++rr) linv[rr] = 1.0f / lacc[rr];
    const int b = bh >> 4, h = bh & 15;
#pragma unroll
    for (int nt = 0; nt < 4; ++nt) {
        int d = nt * 16 + lrow;
#pragma unroll
        for (int rr = 0; rr < 4; ++rr) {
            int srow = wq + lq * 4 + rr;
            size_t idx = ((size_t)b * SS + srow) * HH + h * HD + d;
            ctx[idx] = f2bf(o[nt][rr] * linv[rr]);
        }
    }
}

extern "C" void kernel_launch(void* const* d_in, const int* in_sizes, int n_in,
                              void* d_out, int out_size, void* d_ws, size_t ws_size,
                              hipStream_t stream)
{
    const float* hs = (const float*)d_in[0];
    const float* Wq = (const float*)d_in[1];
    const float* bq = (const float*)d_in[2];
    const float* Wk = (const float*)d_in[3];
    const float* bk = (const float*)d_in[4];
    const float* Wv = (const float*)d_in[5];
    const float* bv = (const float*)d_in[6];
    const float* Wp = (const float*)d_in[7];
    const float* bp = (const float*)d_in[8];

    float* out  = (float*)d_out;
    float* kout = out + (size_t)M * HH;   // K fp32 (final)
    float* vout = kout + (size_t)M * HH;  // V fp32 (final)
    // scratch inside the out region (dead until proj overwrites it):
    unsigned short* WTbuf = (unsigned short*)d_out;                   // 6.3 MB, out[0:16MB)
    unsigned short* qbuf  = (unsigned short*)d_out + (size_t)M * HH;  // 16 MB, out[16:32MB)
    unsigned short* ctx   = (unsigned short*)d_ws;                    // 16 MB

    wT_k<<<dim3(HH / 64, HH / 64, 3), 256, 0, stream>>>(Wq, Wk, Wv, WTbuf);
    qkv_gemm<<<dim3(M / 128, HH / 128, 3), 256, 0, stream>>>(
        hs, WTbuf, bq, bk, bv, qbuf, kout, vout);
    attn_k<<<dim3(SS / 128, BB * NH), 512, 0, stream>>>(qbuf, kout, vout, ctx);
    proj_gemm<<<dim3(M / 128, HH / 128), 256, 0, stream>>>(ctx, Wp, bp, out);
}

// Round 2
// 347.041 us; speedup vs baseline: 1.3172x; 1.1548x over previous
//
#include <hip/hip_runtime.h>

constexpr int BB = 4, SS = 2048, HH = 1024, NH = 16, HD = 64;
constexpr int M = BB * SS;  // 8192 rows for all GEMMs

typedef short          bf16x8 __attribute__((ext_vector_type(8)));
typedef unsigned short u16x8  __attribute__((ext_vector_type(8)));
typedef float          f32x4  __attribute__((ext_vector_type(4)));

// round-half-up bf16 cvt (differs from RNE only on exact ties)
__device__ __forceinline__ unsigned short f2bf(float f) {
    union { float f; unsigned u; } c; c.f = f;
    return (unsigned short)((c.u + 0x8000u) >> 16);
}
__device__ __forceinline__ unsigned packbf2(float lo, float hi) {
    return (unsigned)f2bf(lo) | ((unsigned)f2bf(hi) << 16);
}
__device__ __forceinline__ u16x8 pack8(const float4& x, const float4& y) {
    u16x8 r = { f2bf(x.x), f2bf(x.y), f2bf(x.z), f2bf(x.w),
                f2bf(y.x), f2bf(y.y), f2bf(y.z), f2bf(y.w) };
    return r;
}

// ---------------------------------------------------------------------------
// Wq/Wk/Wv fp32 [k][n] -> bf16 transposed [n][k], 64x64 LDS tiles.
// ---------------------------------------------------------------------------
__global__ __launch_bounds__(256) void wT_k(
    const float* __restrict__ Wq, const float* __restrict__ Wk,
    const float* __restrict__ Wv, unsigned short* __restrict__ WT)
{
    const int z = blockIdx.z;
    const float* W = (z == 0) ? Wq : (z == 1) ? Wk : Wv;
    unsigned short* D = WT + (size_t)z * HH * HH;
    __shared__ __attribute__((aligned(16))) unsigned short T[64][72];

    const int tid = threadIdx.x;
    const int kB = blockIdx.x * 64, nB = blockIdx.y * 64;
    const int r = tid >> 2, c0 = (tid & 3) * 16;
#pragma unroll
    for (int j = 0; j < 4; ++j) {
        float4 w = *(const float4*)(W + (size_t)(kB + r) * HH + nB + c0 + j * 4);
        T[c0 + j * 4 + 0][r] = f2bf(w.x);
        T[c0 + j * 4 + 1][r] = f2bf(w.y);
        T[c0 + j * 4 + 2][r] = f2bf(w.z);
        T[c0 + j * 4 + 3][r] = f2bf(w.w);
    }
    __syncthreads();
    *(u16x8*)(D + (size_t)(nB + r) * HH + kB + c0)     = *(const u16x8*)&T[r][c0];
    *(u16x8*)(D + (size_t)(nB + r) * HH + kB + c0 + 8) = *(const u16x8*)&T[r][c0 + 8];
}

// ---------------------------------------------------------------------------
// QKV GEMM, 128x128 tile, register-prefetched.
// ---------------------------------------------------------------------------
__global__ __launch_bounds__(256) void qkv_gemm(
    const float* __restrict__ X, const unsigned short* __restrict__ WT,
    const float* __restrict__ bq, const float* __restrict__ bk, const float* __restrict__ bv,
    unsigned short* __restrict__ Qd, float* __restrict__ Kd, float* __restrict__ Vd)
{
    const int z = blockIdx.z;
    const unsigned short* Wg = WT + (size_t)z * HH * HH;
    const float* bias = (z == 0) ? bq : (z == 1) ? bk : bv;

    __shared__ __attribute__((aligned(16))) unsigned short Al[128][40];
    __shared__ __attribute__((aligned(16))) unsigned short Bl[128][40];  // Bl[n][k]

    const int tid  = threadIdx.x;
    const int wave = tid >> 6, lane = tid & 63;
    const int lrow = lane & 15, lq = lane >> 4;
    const int rQ = (wave >> 1) * 64, cQ = (wave & 1) * 64;
    const int mBase = blockIdx.x * 128, nBase = blockIdx.y * 128;

    f32x4 acc[4][4] = {};

    const int arow = tid >> 1, acol = (tid & 1) * 16;

    const float*          Ap = X  + (size_t)(mBase + arow) * HH + acol;
    const unsigned short* Bp = Wg + (size_t)(nBase + arow) * HH + acol;

    float4 a[4]; u16x8 b0, b1;
    float4 an[4]; u16x8 b0n, b1n;
#pragma unroll
    for (int c = 0; c < 4; ++c) a[c] = *(const float4*)(Ap + c * 4);
    b0 = *(const u16x8*)Bp; b1 = *(const u16x8*)(Bp + 8);
    Ap += 32; Bp += 32;

    for (int k0 = 0; k0 < HH; k0 += 32) {
        __syncthreads();
        *(u16x8*)&Al[arow][acol]     = pack8(a[0], a[1]);
        *(u16x8*)&Al[arow][acol + 8] = pack8(a[2], a[3]);
        *(u16x8*)&Bl[arow][acol]     = b0;
        *(u16x8*)&Bl[arow][acol + 8] = b1;
        if (k0 + 32 < HH) {
#pragma unroll
            for (int c = 0; c < 4; ++c) an[c] = *(const float4*)(Ap + c * 4);
            b0n = *(const u16x8*)Bp; b1n = *(const u16x8*)(Bp + 8);
            Ap += 32; Bp += 32;
        }
        __syncthreads();

        bf16x8 af[4], bf[4];
#pragma unroll
        for (int i = 0; i < 4; ++i) af[i] = *(const bf16x8*)&Al[rQ + i * 16 + lrow][lq * 8];
#pragma unroll
        for (int j = 0; j < 4; ++j) bf[j] = *(const bf16x8*)&Bl[cQ + j * 16 + lrow][lq * 8];
#pragma unroll
        for (int i = 0; i < 4; ++i)
#pragma unroll
            for (int j = 0; j < 4; ++j)
                acc[i][j] = __builtin_amdgcn_mfma_f32_16x16x32_bf16(af[i], bf[j], acc[i][j], 0, 0, 0);

#pragma unroll
        for (int c = 0; c < 4; ++c) a[c] = an[c];
        b0 = b0n; b1 = b1n;
    }

#pragma unroll
    for (int j = 0; j < 4; ++j) {
        int   n  = nBase + cQ + j * 16 + lrow;
        float bv = bias[n];
        int   h = n >> 6, d = n & 63;
#pragma unroll
        for (int i = 0; i < 4; ++i) {
#pragma unroll
            for (int r = 0; r < 4; ++r) {
                int   m   = mBase + rQ + i * 16 + lq * 4 + r;
                float val = acc[i][j][r] + bv;
                int   b = m >> 11, s = m & (SS - 1);
                size_t idx = ((size_t)(b * NH + h) * SS + s) * HD + d;
                if (z == 0)      Qd[idx] = f2bf(val);
                else if (z == 1) Kd[idx] = val;
                else             Vd[idx] = val;
            }
        }
    }
}

// ---------------------------------------------------------------------------
// Output projection, 128x128, register-prefetched.
// ---------------------------------------------------------------------------
__global__ __launch_bounds__(256) void proj_gemm(
    const unsigned short* __restrict__ X, const float* __restrict__ Wm,
    const float* __restrict__ bias, float* __restrict__ dst)
{
    __shared__ __attribute__((aligned(16))) unsigned short Al[128][40];
    __shared__ __attribute__((aligned(16))) unsigned short Wt[128][40];  // Wt[n][k]

    const int tid  = threadIdx.x;
    const int wave = tid >> 6, lane = tid & 63;
    const int lrow = lane & 15, lq = lane >> 4;
    const int rQ = (wave >> 1) * 64, cQ = (wave & 1) * 64;
    const int mBase = blockIdx.x * 128, nBase = blockIdx.y * 128;

    f32x4 acc[4][4] = {};

    const int arow = tid >> 1, acol = (tid & 1) * 16;
    const int wcol = (tid & 15) * 8, wrow = (tid >> 4) * 2;

    const unsigned short* Ap = X + (size_t)(mBase + arow) * HH + acol;
    const float*          Wp = Wm + (size_t)wrow * HH + nBase + wcol;

    u16x8 a0, a1, a0n, a1n;
    float4 w0a, w0b, w1a, w1b, w0an, w0bn, w1an, w1bn;
    a0 = *(const u16x8*)Ap; a1 = *(const u16x8*)(Ap + 8);
    w0a = *(const float4*)(Wp);      w0b = *(const float4*)(Wp + 4);
    w1a = *(const float4*)(Wp + HH); w1b = *(const float4*)(Wp + HH + 4);
    Ap += 32; Wp += (size_t)32 * HH;

    for (int k0 = 0; k0 < HH; k0 += 32) {
        __syncthreads();
        *(u16x8*)&Al[arow][acol]     = a0;
        *(u16x8*)&Al[arow][acol + 8] = a1;
        *(unsigned*)&Wt[wcol + 0][wrow] = packbf2(w0a.x, w1a.x);
        *(unsigned*)&Wt[wcol + 1][wrow] = packbf2(w0a.y, w1a.y);
        *(unsigned*)&Wt[wcol + 2][wrow] = packbf2(w0a.z, w1a.z);
        *(unsigned*)&Wt[wcol + 3][wrow] = packbf2(w0a.w, w1a.w);
        *(unsigned*)&Wt[wcol + 4][wrow] = packbf2(w0b.x, w1b.x);
        *(unsigned*)&Wt[wcol + 5][wrow] = packbf2(w0b.y, w1b.y);
        *(unsigned*)&Wt[wcol + 6][wrow] = packbf2(w0b.z, w1b.z);
        *(unsigned*)&Wt[wcol + 7][wrow] = packbf2(w0b.w, w1b.w);
        if (k0 + 32 < HH) {
            a0n = *(const u16x8*)Ap; a1n = *(const u16x8*)(Ap + 8);
            w0an = *(const float4*)(Wp);      w0bn = *(const float4*)(Wp + 4);
            w1an = *(const float4*)(Wp + HH); w1bn = *(const float4*)(Wp + HH + 4);
            Ap += 32; Wp += (size_t)32 * HH;
        }
        __syncthreads();

        bf16x8 af[4], bf[4];
#pragma unroll
        for (int i = 0; i < 4; ++i) af[i] = *(const bf16x8*)&Al[rQ + i * 16 + lrow][lq * 8];
#pragma unroll
        for (int j = 0; j < 4; ++j) bf[j] = *(const bf16x8*)&Wt[cQ + j * 16 + lrow][lq * 8];
#pragma unroll
        for (int i = 0; i < 4; ++i)
#pragma unroll
            for (int j = 0; j < 4; ++j)
                acc[i][j] = __builtin_amdgcn_mfma_f32_16x16x32_bf16(af[i], bf[j], acc[i][j], 0, 0, 0);

        a0 = a0n; a1 = a1n;
        w0a = w0an; w0b = w0bn; w1a = w1an; w1b = w1bn;
    }

#pragma unroll
    for (int j = 0; j < 4; ++j) {
        int   n  = nBase + cQ + j * 16 + lrow;
        float bv = bias[n];
#pragma unroll
        for (int i = 0; i < 4; ++i)
#pragma unroll
            for (int r = 0; r < 4; ++r) {
                int m = mBase + rQ + i * 16 + lq * 4 + r;
                dst[(size_t)m * HH + n] = acc[i][j][r] + bv;
            }
    }
}

// ---------------------------------------------------------------------------
// Causal flash attention v3: QBLK=256 / 8 waves (32 q-rows per wave via 2
// row-groups sharing K/V fragment reads) / KVBLK=64.
// - Perfect static balance: grid.x=4; block x processes Q-tiles (7-x, x)
//   sequentially -> every block runs exactly 36 k-tiles; 256 blocks = 1/CU.
// - Q fragments loaded directly global->regs (no Q LDS phase).
// - P buffer [256][64] XOR-swizzled (col ^= 8*(row&7)) -> conflict-free
//   b128 fragment reads; Ks/Vt keep the pad-72 / vsw layouts from v2.
// - No-max online softmax, l via ones-MFMA, register K/V prefetch.
// ---------------------------------------------------------------------------
__global__ __launch_bounds__(512, 2) void attn_k(
    const unsigned short* __restrict__ Qb, const float* __restrict__ Kb,
    const float* __restrict__ Vb, unsigned short* __restrict__ ctx)
{
    __shared__ __attribute__((aligned(16))) unsigned short Ps[256][64];  // swizzled
    __shared__ __attribute__((aligned(16))) unsigned short Ks[64][72];
    __shared__ __attribute__((aligned(16))) unsigned short Vt[64][72];   // Vt[d][s^swz]

    const int tid  = threadIdx.x;
    const int wave = tid >> 6, lane = tid & 63;
    const int lrow = lane & 15, lq = lane >> 4;
    const int bh = blockIdx.y;
    const int b = bh >> 4, h = bh & 15;

    const unsigned short* Q = Qb + (size_t)bh * SS * HD;
    const float*          K = Kb + (size_t)bh * SS * HD;
    const float*          V = Vb + (size_t)bh * SS * HD;

    // K/V staging mapping: 512 threads, 8 floats each
    const int ldr = tid >> 3;          // K/V row 0..63
    const int fck = (tid & 7) * 8;     // 8-col chunk base
    const int vsw = ldr ^ fck;         // swizzled Vt column for this thread

    const short one = (short)0x3F80;   // bf16 1.0
    const bf16x8 ones = { one, one, one, one, one, one, one, one };

    for (int half = 0; half < 2; ++half) {
        const int qb    = (half == 0) ? (7 - blockIdx.x) : blockIdx.x;  // long first
        const int qBase = qb * 256;
        const int wq0   = qBase + wave * 32;  // this wave's first q row

        // Q fragments straight from global (once per Q-tile)
        bf16x8 qf[2][2];
#pragma unroll
        for (int rg = 0; rg < 2; ++rg)
#pragma unroll
            for (int kh = 0; kh < 2; ++kh)
                qf[rg][kh] = *(const bf16x8*)(
                    Q + (size_t)(wq0 + rg * 16 + lrow) * HD + kh * 32 + lq * 8);

        f32x4 o[2][4] = {};
        f32x4 lacc[2] = {};

        float4 ka[2], va[2], kn[2], vn[2];
        {
            const float* Kp = K + (size_t)ldr * HD + fck;
            const float* Vp = V + (size_t)ldr * HD + fck;
            ka[0] = *(const float4*)(Kp); ka[1] = *(const float4*)(Kp + 4);
            va[0] = *(const float4*)(Vp); va[1] = *(const float4*)(Vp + 4);
        }

        const int nkt = 4 * (qb + 1);
        for (int kt = 0; kt < nkt; ++kt) {
            __syncthreads();  // prior iter's Ks/Vt fragment reads done
            *(u16x8*)&Ks[ldr][fck] = pack8(ka[0], ka[1]);
            Vt[fck + 0][vsw] = f2bf(va[0].x);
            Vt[fck + 1][vsw] = f2bf(va[0].y);
            Vt[fck + 2][vsw] = f2bf(va[0].z);
            Vt[fck + 3][vsw] = f2bf(va[0].w);
            Vt[fck + 4][vsw] = f2bf(va[1].x);
            Vt[fck + 5][vsw] = f2bf(va[1].y);
            Vt[fck + 6][vsw] = f2bf(va[1].z);
            Vt[fck + 7][vsw] = f2bf(va[1].w);
            if (kt + 1 < nkt) {  // prefetch next K/V tile
                const float* Kp = K + (size_t)((kt + 1) * 64 + ldr) * HD + fck;
                const float* Vp = V + (size_t)((kt + 1) * 64 + ldr) * HD + fck;
                kn[0] = *(const float4*)(Kp); kn[1] = *(const float4*)(Kp + 4);
                vn[0] = *(const float4*)(Vp); vn[1] = *(const float4*)(Vp + 4);
            }
            __syncthreads();

            const int kbase = kt * 64;
            if (kbase <= wq0 + 31) {  // wave-uniform: not fully masked
                // K fragments, shared by both row-groups
                bf16x8 kf[4][2];
#pragma unroll
                for (int nt = 0; nt < 4; ++nt) {
                    kf[nt][0] = *(const bf16x8*)&Ks[nt * 16 + lrow][lq * 8];
                    kf[nt][1] = *(const bf16x8*)&Ks[nt * 16 + lrow][32 + lq * 8];
                }

#pragma unroll
                for (int rg = 0; rg < 2; ++rg) {
                    f32x4 s[4];
#pragma unroll
                    for (int nt = 0; nt < 4; ++nt) {
                        f32x4 t = {};
                        t = __builtin_amdgcn_mfma_f32_16x16x32_bf16(qf[rg][0], kf[nt][0], t, 0, 0, 0);
                        t = __builtin_amdgcn_mfma_f32_16x16x32_bf16(qf[rg][1], kf[nt][1], t, 0, 0, 0);
                        s[nt] = t;
                    }
#pragma unroll
                    for (int nt = 0; nt < 4; ++nt)
#pragma unroll
                        for (int rr = 0; rr < 4; ++rr) s[nt][rr] *= 0.125f;
                    const int rq = wq0 + rg * 16;  // row-group base
                    if (kbase + 63 > rq) {         // diagonal region -> element mask
#pragma unroll
                        for (int nt = 0; nt < 4; ++nt)
#pragma unroll
                            for (int rr = 0; rr < 4; ++rr)
                                if (kbase + nt * 16 + lrow > rq + lq * 4 + rr)
                                    s[nt][rr] = -1e30f;
                    }
                    // P = exp(S) -> swizzled scatter into wave-private rows
#pragma unroll
                    for (int nt = 0; nt < 4; ++nt)
#pragma unroll
                        for (int rr = 0; rr < 4; ++rr) {
                            const int pr = wave * 32 + rg * 16 + lq * 4 + rr;
                            const int pc = (nt * 16 + lrow) ^ (8 * ((lq * 4 + rr) & 7));
                            Ps[pr][pc] = f2bf(__expf(s[nt][rr]));
                        }
                }

                // P fragments (swizzled read), l, and PV with shared V frags
                bf16x8 pf[2][2];
#pragma unroll
                for (int rg = 0; rg < 2; ++rg) {
                    const int pr  = wave * 32 + rg * 16 + lrow;
                    const int swz = 8 * (lrow & 7);
                    pf[rg][0] = *(const bf16x8*)&Ps[pr][(lq * 8) ^ swz];
                    pf[rg][1] = *(const bf16x8*)&Ps[pr][(32 + lq * 8) ^ swz];
                    lacc[rg] = __builtin_amdgcn_mfma_f32_16x16x32_bf16(pf[rg][0], ones, lacc[rg], 0, 0, 0);
                    lacc[rg] = __builtin_amdgcn_mfma_f32_16x16x32_bf16(pf[rg][1], ones, lacc[rg], 0, 0, 0);
                }
#pragma unroll
                for (int nt = 0; nt < 4; ++nt) {
                    const int row  = nt * 16 + lrow;
                    const int cswz = (row >> 3) << 3;
                    bf16x8 vf0 = *(const bf16x8*)&Vt[row][(lq * 8) ^ cswz];
                    bf16x8 vf1 = *(const bf16x8*)&Vt[row][(32 + lq * 8) ^ cswz];
#pragma unroll
                    for (int rg = 0; rg < 2; ++rg) {
                        o[rg][nt] = __builtin_amdgcn_mfma_f32_16x16x32_bf16(pf[rg][0], vf0, o[rg][nt], 0, 0, 0);
                        o[rg][nt] = __builtin_amdgcn_mfma_f32_16x16x32_bf16(pf[rg][1], vf1, o[rg][nt], 0, 0, 0);
                    }
                }
            }

            ka[0] = kn[0]; ka[1] = kn[1]; va[0] = vn[0]; va[1] = vn[1];
        }

        // epilogue: O /= l, write ctx bf16 as [b, s, h*HD + d]
#pragma unroll
        for (int rg = 0; rg < 2; ++rg) {
            float linv[4];
#pragma unroll
            for (int rr = 0; rr < 4; ++rr) linv[rr] = 1.0f / lacc[rg][rr];
#pragma unroll
            for (int nt = 0; nt < 4; ++nt) {
                const int d = nt * 16 + lrow;
#pragma unroll
                for (int rr = 0; rr < 4; ++rr) {
                    const int srow = wq0 + rg * 16 + lq * 4 + rr;
                    size_t idx = ((size_t)b * SS + srow) * HH + h * HD + d;
                    ctx[idx] = f2bf(o[rg][nt][rr] * linv[rr]);
                }
            }
        }
    }
}

extern "C" void kernel_launch(void* const* d_in, const int* in_sizes, int n_in,
                              void* d_out, int out_size, void* d_ws, size_t ws_size,
                              hipStream_t stream)
{
    const float* hs = (const float*)d_in[0];
    const float* Wq = (const float*)d_in[1];
    const float* bq = (const float*)d_in[2];
    const float* Wk = (const float*)d_in[3];
    const float* bk = (const float*)d_in[4];
    const float* Wv = (const float*)d_in[5];
    const float* bv = (const float*)d_in[6];
    const float* Wp = (const float*)d_in[7];
    const float* bp = (const float*)d_in[8];

    float* out  = (float*)d_out;
    float* kout = out + (size_t)M * HH;   // K fp32 (final)
    float* vout = kout + (size_t)M * HH;  // V fp32 (final)
    // scratch inside the out region (dead until proj overwrites it):
    unsigned short* WTbuf = (unsigned short*)d_out;                   // 6.3 MB
    unsigned short* qbuf  = (unsigned short*)d_out + (size_t)M * HH;  // 16 MB
    unsigned short* ctx   = (unsigned short*)d_ws;                    // 16 MB

    wT_k<<<dim3(HH / 64, HH / 64, 3), 256, 0, stream>>>(Wq, Wk, Wv, WTbuf);
    qkv_gemm<<<dim3(M / 128, HH / 128, 3), 256, 0, stream>>>(
        hs, WTbuf, bq, bk, bv, qbuf, kout, vout);
    attn_k<<<dim3(4, BB * NH), 512, 0, stream>>>(qbuf, kout, vout, ctx);
    proj_gemm<<<dim3(M / 128, HH / 128), 256, 0, stream>>>(ctx, Wp, bp, out);
}

// Round 3
// 315.272 us; speedup vs baseline: 1.4500x; 1.1008x over previous
//
#include <hip/hip_runtime.h>

constexpr int BB = 4, SS = 2048, HH = 1024, NH = 16, HD = 64;
constexpr int M = BB * SS;  // 8192 rows for all GEMMs

typedef short          bf16x8 __attribute__((ext_vector_type(8)));
typedef unsigned short u16x8  __attribute__((ext_vector_type(8)));
typedef float          f32x4  __attribute__((ext_vector_type(4)));

// round-half-up bf16 cvt (differs from RNE only on exact ties)
__device__ __forceinline__ unsigned short f2bf(float f) {
    union { float f; unsigned u; } c; c.f = f;
    return (unsigned short)((c.u + 0x8000u) >> 16);
}
__device__ __forceinline__ unsigned packbf2(float lo, float hi) {
    return (unsigned)f2bf(lo) | ((unsigned)f2bf(hi) << 16);
}
__device__ __forceinline__ u16x8 pack8(const float4& x, const float4& y) {
    u16x8 r = { f2bf(x.x), f2bf(x.y), f2bf(x.z), f2bf(x.w),
                f2bf(y.x), f2bf(y.y), f2bf(y.z), f2bf(y.w) };
    return r;
}

// global -> LDS direct DMA, 16B per lane.  LDS dest is wave-uniform base +
// lane*16 (HW rule); global src is per-lane.
__device__ __forceinline__ void gld_lds16(const unsigned short* g, unsigned short* l) {
    __builtin_amdgcn_global_load_lds(
        (const __attribute__((address_space(1))) unsigned int*)(const void*)g,
        (__attribute__((address_space(3))) unsigned int*)(void*)l,
        16, 0, 0);
}

// ---------------------------------------------------------------------------
// One fp32 [k][n] matrix -> bf16 transposed [n][k], 64x64 LDS tiles.
// ---------------------------------------------------------------------------
__global__ __launch_bounds__(256) void wT1_k(
    const float* __restrict__ W, unsigned short* __restrict__ D)
{
    __shared__ __attribute__((aligned(16))) unsigned short T[64][72];

    const int tid = threadIdx.x;
    const int kB = blockIdx.x * 64, nB = blockIdx.y * 64;
    const int r = tid >> 2, c0 = (tid & 3) * 16;
#pragma unroll
    for (int j = 0; j < 4; ++j) {
        float4 w = *(const float4*)(W + (size_t)(kB + r) * HH + nB + c0 + j * 4);
        T[c0 + j * 4 + 0][r] = f2bf(w.x);
        T[c0 + j * 4 + 1][r] = f2bf(w.y);
        T[c0 + j * 4 + 2][r] = f2bf(w.z);
        T[c0 + j * 4 + 3][r] = f2bf(w.w);
    }
    __syncthreads();
    *(u16x8*)(D + (size_t)(nB + r) * HH + kB + c0)     = *(const u16x8*)&T[r][c0];
    *(u16x8*)(D + (size_t)(nB + r) * HH + kB + c0 + 8) = *(const u16x8*)&T[r][c0 + 8];
}

// ---------------------------------------------------------------------------
// X fp32 -> bf16, one shot (8.4M elems, ~50 MB traffic).
// ---------------------------------------------------------------------------
__global__ __launch_bounds__(256) void xbf_k(
    const float* __restrict__ X, unsigned short* __restrict__ Xb)
{
    const size_t i = ((size_t)blockIdx.x * 256 + threadIdx.x) * 8;
    float4 x0 = *(const float4*)(X + i);
    float4 x1 = *(const float4*)(X + i + 4);
    *(u16x8*)(Xb + i) = pack8(x0, x1);
}

// ---------------------------------------------------------------------------
// QKV GEMM, m97 structure: 128x128 tile, BK=32, both operands bf16 staged
// via global_load_lds (width 16) into linear LDS, 2 barriers per K-step.
// A = Xbf [m][k], B = WT[z][n][k].  Epilogue scatters to [b,nh,s,hd].
// ---------------------------------------------------------------------------
__global__ __launch_bounds__(256) void qkv_gemm(
    const unsigned short* __restrict__ Xb, const unsigned short* __restrict__ WT,
    const float* __restrict__ bq, const float* __restrict__ bk, const float* __restrict__ bv,
    unsigned short* __restrict__ Qd, float* __restrict__ Kd, float* __restrict__ Vd)
{
    const int z = blockIdx.z;
    const unsigned short* Wg = WT + (size_t)z * HH * HH;
    const float* bias = (z == 0) ? bq : (z == 1) ? bk : bv;

    __shared__ __attribute__((aligned(16))) unsigned short As[128 * 32];
    __shared__ __attribute__((aligned(16))) unsigned short Bs[128 * 32];

    const int tid  = threadIdx.x;
    const int wave = tid >> 6, lane = tid & 63;
    const int lrow = lane & 15, lq = lane >> 4;
    const int rQ = (wave >> 1) * 64, cQ = (wave & 1) * 64;
    const int mBase = blockIdx.x * 128, nBase = blockIdx.y * 128;

    f32x4 acc[4][4] = {};

    // staging: wave w owns 1KB chunks 2w, 2w+1 of each tile; chunk c covers
    // rows 16c..16c+15 (32 bf16 each); lane l -> row c*16 + l/4, col (l&3)*8
    const int srow = lane >> 2, scol = (lane & 3) * 8;
    const int c0 = wave * 2, c1 = wave * 2 + 1;

    const unsigned short* ga0 = Xb + (size_t)(mBase + c0 * 16 + srow) * HH + scol;
    const unsigned short* ga1 = Xb + (size_t)(mBase + c1 * 16 + srow) * HH + scol;
    const unsigned short* gb0 = Wg + (size_t)(nBase + c0 * 16 + srow) * HH + scol;
    const unsigned short* gb1 = Wg + (size_t)(nBase + c1 * 16 + srow) * HH + scol;
    unsigned short* la0 = &As[c0 * 512];
    unsigned short* la1 = &As[c1 * 512];
    unsigned short* lb0 = &Bs[c0 * 512];
    unsigned short* lb1 = &Bs[c1 * 512];

    for (int k0 = 0; k0 < HH; k0 += 32) {
        __syncthreads();  // prior iter's fragment reads done
        gld_lds16(ga0 + k0, la0);
        gld_lds16(ga1 + k0, la1);
        gld_lds16(gb0 + k0, lb0);
        gld_lds16(gb1 + k0, lb1);
        __syncthreads();  // staging complete (vmcnt(0) drained by barrier)

        bf16x8 af[4], bf[4];
#pragma unroll
        for (int i = 0; i < 4; ++i)
            af[i] = *(const bf16x8*)&As[(rQ + i * 16 + lrow) * 32 + lq * 8];
#pragma unroll
        for (int j = 0; j < 4; ++j)
            bf[j] = *(const bf16x8*)&Bs[(cQ + j * 16 + lrow) * 32 + lq * 8];
#pragma unroll
        for (int i = 0; i < 4; ++i)
#pragma unroll
            for (int j = 0; j < 4; ++j)
                acc[i][j] = __builtin_amdgcn_mfma_f32_16x16x32_bf16(af[i], bf[j], acc[i][j], 0, 0, 0);
    }

#pragma unroll
    for (int j = 0; j < 4; ++j) {
        int   n  = nBase + cQ + j * 16 + lrow;
        float bv = bias[n];
        int   h = n >> 6, d = n & 63;
#pragma unroll
        for (int i = 0; i < 4; ++i) {
#pragma unroll
            for (int r = 0; r < 4; ++r) {
                int   m   = mBase + rQ + i * 16 + lq * 4 + r;
                float val = acc[i][j][r] + bv;
                int   b = m >> 11, s = m & (SS - 1);
                size_t idx = ((size_t)(b * NH + h) * SS + s) * HD + d;
                if (z == 0)      Qd[idx] = f2bf(val);
                else if (z == 1) Kd[idx] = val;
                else             Vd[idx] = val;
            }
        }
    }
}

// ---------------------------------------------------------------------------
// Output projection, m97 structure (requires pre-transposed bf16 Wp in ws).
// ---------------------------------------------------------------------------
__global__ __launch_bounds__(256) void proj_bf(
    const unsigned short* __restrict__ Xc, const unsigned short* __restrict__ WTp,
    const float* __restrict__ bias, float* __restrict__ dst)
{
    __shared__ __attribute__((aligned(16))) unsigned short As[128 * 32];
    __shared__ __attribute__((aligned(16))) unsigned short Bs[128 * 32];

    const int tid  = threadIdx.x;
    const int wave = tid >> 6, lane = tid & 63;
    const int lrow = lane & 15, lq = lane >> 4;
    const int rQ = (wave >> 1) * 64, cQ = (wave & 1) * 64;
    const int mBase = blockIdx.x * 128, nBase = blockIdx.y * 128;

    f32x4 acc[4][4] = {};

    const int srow = lane >> 2, scol = (lane & 3) * 8;
    const int c0 = wave * 2, c1 = wave * 2 + 1;

    const unsigned short* ga0 = Xc  + (size_t)(mBase + c0 * 16 + srow) * HH + scol;
    const unsigned short* ga1 = Xc  + (size_t)(mBase + c1 * 16 + srow) * HH + scol;
    const unsigned short* gb0 = WTp + (size_t)(nBase + c0 * 16 + srow) * HH + scol;
    const unsigned short* gb1 = WTp + (size_t)(nBase + c1 * 16 + srow) * HH + scol;
    unsigned short* la0 = &As[c0 * 512];
    unsigned short* la1 = &As[c1 * 512];
    unsigned short* lb0 = &Bs[c0 * 512];
    unsigned short* lb1 = &Bs[c1 * 512];

    for (int k0 = 0; k0 < HH; k0 += 32) {
        __syncthreads();
        gld_lds16(ga0 + k0, la0);
        gld_lds16(ga1 + k0, la1);
        gld_lds16(gb0 + k0, lb0);
        gld_lds16(gb1 + k0, lb1);
        __syncthreads();

        bf16x8 af[4], bf[4];
#pragma unroll
        for (int i = 0; i < 4; ++i)
            af[i] = *(const bf16x8*)&As[(rQ + i * 16 + lrow) * 32 + lq * 8];
#pragma unroll
        for (int j = 0; j < 4; ++j)
            bf[j] = *(const bf16x8*)&Bs[(cQ + j * 16 + lrow) * 32 + lq * 8];
#pragma unroll
        for (int i = 0; i < 4; ++i)
#pragma unroll
            for (int j = 0; j < 4; ++j)
                acc[i][j] = __builtin_amdgcn_mfma_f32_16x16x32_bf16(af[i], bf[j], acc[i][j], 0, 0, 0);
    }

#pragma unroll
    for (int j = 0; j < 4; ++j) {
        int   n  = nBase + cQ + j * 16 + lrow;
        float bv = bias[n];
#pragma unroll
        for (int i = 0; i < 4; ++i)
#pragma unroll
            for (int r = 0; r < 4; ++r) {
                int m = mBase + rQ + i * 16 + lq * 4 + r;
                dst[(size_t)m * HH + n] = acc[i][j][r] + bv;
            }
    }
}

// ---------------------------------------------------------------------------
// Fallback output projection (W fp32 transposed in-kernel) for small ws.
// ---------------------------------------------------------------------------
__global__ __launch_bounds__(256) void proj_gemm(
    const unsigned short* __restrict__ X, const float* __restrict__ Wm,
    const float* __restrict__ bias, float* __restrict__ dst)
{
    __shared__ __attribute__((aligned(16))) unsigned short Al[128][40];
    __shared__ __attribute__((aligned(16))) unsigned short Wt[128][40];  // Wt[n][k]

    const int tid  = threadIdx.x;
    const int wave = tid >> 6, lane = tid & 63;
    const int lrow = lane & 15, lq = lane >> 4;
    const int rQ = (wave >> 1) * 64, cQ = (wave & 1) * 64;
    const int mBase = blockIdx.x * 128, nBase = blockIdx.y * 128;

    f32x4 acc[4][4] = {};

    const int arow = tid >> 1, acol = (tid & 1) * 16;
    const int wcol = (tid & 15) * 8, wrow = (tid >> 4) * 2;

    const unsigned short* Ap = X + (size_t)(mBase + arow) * HH + acol;
    const float*          Wp = Wm + (size_t)wrow * HH + nBase + wcol;

    u16x8 a0, a1, a0n, a1n;
    float4 w0a, w0b, w1a, w1b, w0an, w0bn, w1an, w1bn;
    a0 = *(const u16x8*)Ap; a1 = *(const u16x8*)(Ap + 8);
    w0a = *(const float4*)(Wp);      w0b = *(const float4*)(Wp + 4);
    w1a = *(const float4*)(Wp + HH); w1b = *(const float4*)(Wp + HH + 4);
    Ap += 32; Wp += (size_t)32 * HH;

    for (int k0 = 0; k0 < HH; k0 += 32) {
        __syncthreads();
        *(u16x8*)&Al[arow][acol]     = a0;
        *(u16x8*)&Al[arow][acol + 8] = a1;
        *(unsigned*)&Wt[wcol + 0][wrow] = packbf2(w0a.x, w1a.x);
        *(unsigned*)&Wt[wcol + 1][wrow] = packbf2(w0a.y, w1a.y);
        *(unsigned*)&Wt[wcol + 2][wrow] = packbf2(w0a.z, w1a.z);
        *(unsigned*)&Wt[wcol + 3][wrow] = packbf2(w0a.w, w1a.w);
        *(unsigned*)&Wt[wcol + 4][wrow] = packbf2(w0b.x, w1b.x);
        *(unsigned*)&Wt[wcol + 5][wrow] = packbf2(w0b.y, w1b.y);
        *(unsigned*)&Wt[wcol + 6][wrow] = packbf2(w0b.z, w1b.z);
        *(unsigned*)&Wt[wcol + 7][wrow] = packbf2(w0b.w, w1b.w);
        if (k0 + 32 < HH) {
            a0n = *(const u16x8*)Ap; a1n = *(const u16x8*)(Ap + 8);
            w0an = *(const float4*)(Wp);      w0bn = *(const float4*)(Wp + 4);
            w1an = *(const float4*)(Wp + HH); w1bn = *(const float4*)(Wp + HH + 4);
            Ap += 32; Wp += (size_t)32 * HH;
        }
        __syncthreads();

        bf16x8 af[4], bf[4];
#pragma unroll
        for (int i = 0; i < 4; ++i) af[i] = *(const bf16x8*)&Al[rQ + i * 16 + lrow][lq * 8];
#pragma unroll
        for (int j = 0; j < 4; ++j) bf[j] = *(const bf16x8*)&Wt[cQ + j * 16 + lrow][lq * 8];
#pragma unroll
        for (int i = 0; i < 4; ++i)
#pragma unroll
            for (int j = 0; j < 4; ++j)
                acc[i][j] = __builtin_amdgcn_mfma_f32_16x16x32_bf16(af[i], bf[j], acc[i][j], 0, 0, 0);

        a0 = a0n; a1 = a1n;
        w0a = w0an; w0b = w0bn; w1a = w1an; w1b = w1bn;
    }

#pragma unroll
    for (int j = 0; j < 4; ++j) {
        int   n  = nBase + cQ + j * 16 + lrow;
        float bv = bias[n];
#pragma unroll
        for (int i = 0; i < 4; ++i)
#pragma unroll
            for (int r = 0; r < 4; ++r) {
                int m = mBase + rQ + i * 16 + lq * 4 + r;
                dst[(size_t)m * HH + n] = acc[i][j][r] + bv;
            }
    }
}

// ---------------------------------------------------------------------------
// Causal flash attention v3 (unchanged from round 2): QBLK=256 / 8 waves /
// KVBLK=64, perfectly balanced causal pairing, swizzled P buffer.
// ---------------------------------------------------------------------------
__global__ __launch_bounds__(512, 2) void attn_k(
    const unsigned short* __restrict__ Qb, const float* __restrict__ Kb,
    const float* __restrict__ Vb, unsigned short* __restrict__ ctx)
{
    __shared__ __attribute__((aligned(16))) unsigned short Ps[256][64];  // swizzled
    __shared__ __attribute__((aligned(16))) unsigned short Ks[64][72];
    __shared__ __attribute__((aligned(16))) unsigned short Vt[64][72];   // Vt[d][s^swz]

    const int tid  = threadIdx.x;
    const int wave = tid >> 6, lane = tid & 63;
    const int lrow = lane & 15, lq = lane >> 4;
    const int bh = blockIdx.y;
    const int b = bh >> 4, h = bh & 15;

    const unsigned short* Q = Qb + (size_t)bh * SS * HD;
    const float*          K = Kb + (size_t)bh * SS * HD;
    const float*          V = Vb + (size_t)bh * SS * HD;

    const int ldr = tid >> 3;          // K/V row 0..63
    const int fck = (tid & 7) * 8;     // 8-col chunk base
    const int vsw = ldr ^ fck;         // swizzled Vt column for this thread

    const short one = (short)0x3F80;   // bf16 1.0
    const bf16x8 ones = { one, one, one, one, one, one, one, one };

    for (int half = 0; half < 2; ++half) {
        const int qb    = (half == 0) ? (7 - blockIdx.x) : blockIdx.x;  // long first
        const int qBase = qb * 256;
        const int wq0   = qBase + wave * 32;  // this wave's first q row

        bf16x8 qf[2][2];
#pragma unroll
        for (int rg = 0; rg < 2; ++rg)
#pragma unroll
            for (int kh = 0; kh < 2; ++kh)
                qf[rg][kh] = *(const bf16x8*)(
                    Q + (size_t)(wq0 + rg * 16 + lrow) * HD + kh * 32 + lq * 8);

        f32x4 o[2][4] = {};
        f32x4 lacc[2] = {};

        float4 ka[2], va[2], kn[2], vn[2];
        {
            const float* Kp = K + (size_t)ldr * HD + fck;
            const float* Vp = V + (size_t)ldr * HD + fck;
            ka[0] = *(const float4*)(Kp); ka[1] = *(const float4*)(Kp + 4);
            va[0] = *(const float4*)(Vp); va[1] = *(const float4*)(Vp + 4);
        }

        const int nkt = 4 * (qb + 1);
        for (int kt = 0; kt < nkt; ++kt) {
            __syncthreads();
            *(u16x8*)&Ks[ldr][fck] = pack8(ka[0], ka[1]);
            Vt[fck + 0][vsw] = f2bf(va[0].x);
            Vt[fck + 1][vsw] = f2bf(va[0].y);
            Vt[fck + 2][vsw] = f2bf(va[0].z);
            Vt[fck + 3][vsw] = f2bf(va[0].w);
            Vt[fck + 4][vsw] = f2bf(va[1].x);
            Vt[fck + 5][vsw] = f2bf(va[1].y);
            Vt[fck + 6][vsw] = f2bf(va[1].z);
            Vt[fck + 7][vsw] = f2bf(va[1].w);
            if (kt + 1 < nkt) {
                const float* Kp = K + (size_t)((kt + 1) * 64 + ldr) * HD + fck;
                const float* Vp = V + (size_t)((kt + 1) * 64 + ldr) * HD + fck;
                kn[0] = *(const float4*)(Kp); kn[1] = *(const float4*)(Kp + 4);
                vn[0] = *(const float4*)(Vp); vn[1] = *(const float4*)(Vp + 4);
            }
            __syncthreads();

            const int kbase = kt * 64;
            if (kbase <= wq0 + 31) {
                bf16x8 kf[4][2];
#pragma unroll
                for (int nt = 0; nt < 4; ++nt) {
                    kf[nt][0] = *(const bf16x8*)&Ks[nt * 16 + lrow][lq * 8];
                    kf[nt][1] = *(const bf16x8*)&Ks[nt * 16 + lrow][32 + lq * 8];
                }

#pragma unroll
                for (int rg = 0; rg < 2; ++rg) {
                    f32x4 s[4];
#pragma unroll
                    for (int nt = 0; nt < 4; ++nt) {
                        f32x4 t = {};
                        t = __builtin_amdgcn_mfma_f32_16x16x32_bf16(qf[rg][0], kf[nt][0], t, 0, 0, 0);
                        t = __builtin_amdgcn_mfma_f32_16x16x32_bf16(qf[rg][1], kf[nt][1], t, 0, 0, 0);
                        s[nt] = t;
                    }
#pragma unroll
                    for (int nt = 0; nt < 4; ++nt)
#pragma unroll
                        for (int rr = 0; rr < 4; ++rr) s[nt][rr] *= 0.125f;
                    const int rq = wq0 + rg * 16;
                    if (kbase + 63 > rq) {
#pragma unroll
                        for (int nt = 0; nt < 4; ++nt)
#pragma unroll
                            for (int rr = 0; rr < 4; ++rr)
                                if (kbase + nt * 16 + lrow > rq + lq * 4 + rr)
                                    s[nt][rr] = -1e30f;
                    }
#pragma unroll
                    for (int nt = 0; nt < 4; ++nt)
#pragma unroll
                        for (int rr = 0; rr < 4; ++rr) {
                            const int pr = wave * 32 + rg * 16 + lq * 4 + rr;
                            const int pc = (nt * 16 + lrow) ^ (8 * ((lq * 4 + rr) & 7));
                            Ps[pr][pc] = f2bf(__expf(s[nt][rr]));
                        }
                }

                bf16x8 pf[2][2];
#pragma unroll
                for (int rg = 0; rg < 2; ++rg) {
                    const int pr  = wave * 32 + rg * 16 + lrow;
                    const int swz = 8 * (lrow & 7);
                    pf[rg][0] = *(const bf16x8*)&Ps[pr][(lq * 8) ^ swz];
                    pf[rg][1] = *(const bf16x8*)&Ps[pr][(32 + lq * 8) ^ swz];
                    lacc[rg] = __builtin_amdgcn_mfma_f32_16x16x32_bf16(pf[rg][0], ones, lacc[rg], 0, 0, 0);
                    lacc[rg] = __builtin_amdgcn_mfma_f32_16x16x32_bf16(pf[rg][1], ones, lacc[rg], 0, 0, 0);
                }
#pragma unroll
                for (int nt = 0; nt < 4; ++nt) {
                    const int row  = nt * 16 + lrow;
                    const int cswz = (row >> 3) << 3;
                    bf16x8 vf0 = *(const bf16x8*)&Vt[row][(lq * 8) ^ cswz];
                    bf16x8 vf1 = *(const bf16x8*)&Vt[row][(32 + lq * 8) ^ cswz];
#pragma unroll
                    for (int rg = 0; rg < 2; ++rg) {
                        o[rg][nt] = __builtin_amdgcn_mfma_f32_16x16x32_bf16(pf[rg][0], vf0, o[rg][nt], 0, 0, 0);
                        o[rg][nt] = __builtin_amdgcn_mfma_f32_16x16x32_bf16(pf[rg][1], vf1, o[rg][nt], 0, 0, 0);
                    }
                }
            }

            ka[0] = kn[0]; ka[1] = kn[1]; va[0] = vn[0]; va[1] = vn[1];
        }

#pragma unroll
        for (int rg = 0; rg < 2; ++rg) {
            float linv[4];
#pragma unroll
            for (int rr = 0; rr < 4; ++rr) linv[rr] = 1.0f / lacc[rg][rr];
#pragma unroll
            for (int nt = 0; nt < 4; ++nt) {
                const int d = nt * 16 + lrow;
#pragma unroll
                for (int rr = 0; rr < 4; ++rr) {
                    const int srow = wq0 + rg * 16 + lq * 4 + rr;
                    size_t idx = ((size_t)b * SS + srow) * HH + h * HD + d;
                    ctx[idx] = f2bf(o[rg][nt][rr] * linv[rr]);
                }
            }
        }
    }
}

extern "C" void kernel_launch(void* const* d_in, const int* in_sizes, int n_in,
                              void* d_out, int out_size, void* d_ws, size_t ws_size,
                              hipStream_t stream)
{
    const float* hs = (const float*)d_in[0];
    const float* Wq = (const float*)d_in[1];
    const float* bq = (const float*)d_in[2];
    const float* Wk = (const float*)d_in[3];
    const float* bk = (const float*)d_in[4];
    const float* Wv = (const float*)d_in[5];
    const float* bv = (const float*)d_in[6];
    const float* Wp = (const float*)d_in[7];
    const float* bp = (const float*)d_in[8];

    float* out  = (float*)d_out;
    float* kout = out + (size_t)M * HH;   // K fp32 (final)
    float* vout = kout + (size_t)M * HH;  // V fp32 (final)
    // scratch inside the out region (dead before proj overwrites it):
    unsigned short* WTbuf = (unsigned short*)d_out;                   // 6.3 MB, dead after qkv
    unsigned short* qbuf  = (unsigned short*)d_out + (size_t)M * HH;  // 16.8 MB, dead after attn
    // ws scratch: Xbf lives until qkv; ctx (attn output) reuses the same bytes
    unsigned short* Xbf = (unsigned short*)d_ws;                      // 16.8 MB
    unsigned short* ctx = (unsigned short*)d_ws;                      // 16.8 MB (after qkv)
    const size_t wsNeedBF = (size_t)M * HH * 2 + (size_t)HH * HH * 2;
    const bool   wsBig    = ws_size >= wsNeedBF;
    unsigned short* WTp = (unsigned short*)d_ws + (size_t)M * HH;     // 2.1 MB, iff wsBig

    xbf_k<<<dim3(M * HH / (256 * 8)), 256, 0, stream>>>(hs, Xbf);
    wT1_k<<<dim3(HH / 64, HH / 64), 256, 0, stream>>>(Wq, WTbuf);
    wT1_k<<<dim3(HH / 64, HH / 64), 256, 0, stream>>>(Wk, WTbuf + (size_t)HH * HH);
    wT1_k<<<dim3(HH / 64, HH / 64), 256, 0, stream>>>(Wv, WTbuf + (size_t)2 * HH * HH);
    if (wsBig)
        wT1_k<<<dim3(HH / 64, HH / 64), 256, 0, stream>>>(Wp, WTp);
    qkv_gemm<<<dim3(M / 128, HH / 128, 3), 256, 0, stream>>>(
        Xbf, WTbuf, bq, bk, bv, qbuf, kout, vout);
    attn_k<<<dim3(4, BB * NH), 512, 0, stream>>>(qbuf, kout, vout, ctx);
    if (wsBig)
        proj_bf<<<dim3(M / 128, HH / 128), 256, 0, stream>>>(ctx, WTp, bp, out);
    else
        proj_gemm<<<dim3(M / 128, HH / 128), 256, 0, stream>>>(ctx, Wp, bp, out);
}